// Round 13
// baseline (230.850 us; speedup 1.0000x reference)
//
#include <hip/hip_runtime.h>

// DoReFa dense: out = q_in(3-bit) @ (sign(W)*E) + b,  E = mean|W|
//   out[i,j] = (E/7) * sum_k r[i,k]*sign(W[k,j]),  r in 0..7 -- exact in i8 MFMA.
// R13: R12 data path (AFRAG global->reg, B-only LDS) + A-register PREFETCH:
//      A-frags for tile T+1 load during tile T's MFMA (aA/aB ping-pong, 6-tile
//      unroll), gate vmcnt(1) forces {B(T) staged, A(T) in regs}, leaves B(T+1)
//      stage in flight. Fixes R12's per-tile L2-latency serialization.

static constexpr int BATCH  = 8192;
static constexpr int IN_CH  = 4096;
static constexpr int NUNITS = 4096;
static constexpr int TPB    = 256;

typedef int v4i __attribute__((ext_vector_type(4)));

// ---- workspace layout ----
static constexpr size_t AF_OFF   = 0;                        // AFRAG[512][64][64][16]
static constexpr size_t AF_BYTES = (size_t)BATCH * IN_CH;    // 32 MB
static constexpr size_t BT_OFF   = AF_OFF + AF_BYTES;
static constexpr size_t BT_BYTES = (size_t)NUNITS * IN_CH;   // 16 MB
static constexpr int    NPART    = 4096;
static constexpr size_t PART_OFF = BT_OFF + BT_BYTES;
static constexpr size_t SCALE_OFF= PART_OFF + NPART * sizeof(float);

// -------------------------- sign(W) transpose to [N][K]  +  fused |W| partial sum
__global__ __launch_bounds__(TPB) void k_signT(const float* __restrict__ W,
                                               char* __restrict__ bt,
                                               float* __restrict__ partials) {
    __shared__ char tile[64][68];
    __shared__ float red[TPB];
    const int bk = blockIdx.x & 63;
    const int bn = blockIdx.x >> 6;
    const int t  = threadIdx.x;
    const int c  = t & 63;
    const int r0 = t >> 6;
    float asum = 0.f;
#pragma unroll
    for (int i = 0; i < 16; ++i) {
        int r = i * 4 + r0;
        float w = W[(size_t)(bk * 64 + r) * NUNITS + bn * 64 + c];
        asum += fabsf(w);
        tile[c][r] = (w > 0.f) ? 1 : ((w < 0.f) ? -1 : 0);
    }
    __syncthreads();
    const int n  = t >> 2;
    const int kk = (t & 3) * 16;
    char o[16];
#pragma unroll
    for (int j = 0; j < 16; ++j) o[j] = tile[n][kk + j];
    *(uint4*)(bt + (size_t)(bn * 64 + n) * IN_CH + bk * 64 + kk) = *(const uint4*)o;

    red[t] = asum;
    __syncthreads();
    for (int off = TPB / 2; off > 0; off >>= 1) {
        if (t < off) red[t] += red[t + off];
        __syncthreads();
    }
    if (t == 0) partials[blockIdx.x] = red[0];
}

// ------------------------------------------------------------- quantize A -> AFRAG
// AFRAG[mt][kt][lane][16]: element (lane, j) = q(x[mt*16 + (lane&15)][kt*64 + (lane>>4)*16 + j])
__device__ __forceinline__ unsigned int q4(float4 v) {
    unsigned int b0 = (unsigned int)(int)rintf(fminf(1.0f, fabsf(v.x)) * 7.0f);
    unsigned int b1 = (unsigned int)(int)rintf(fminf(1.0f, fabsf(v.y)) * 7.0f);
    unsigned int b2 = (unsigned int)(int)rintf(fminf(1.0f, fabsf(v.z)) * 7.0f);
    unsigned int b3 = (unsigned int)(int)rintf(fminf(1.0f, fabsf(v.w)) * 7.0f);
    return b0 | (b1 << 8) | (b2 << 16) | (b3 << 24);
}

__global__ __launch_bounds__(TPB) void k_quant_a(const float* __restrict__ x,
                                                 char* __restrict__ af,
                                                 const float* __restrict__ partials,
                                                 float* __restrict__ scale) {
    if (blockIdx.x == 0) {
        __shared__ float red[TPB];
        float s = 0.f;
        for (int i = threadIdx.x; i < NPART; i += TPB) s += partials[i];
        red[threadIdx.x] = s;
        __syncthreads();
        for (int off = TPB / 2; off > 0; off >>= 1) {
            if ((int)threadIdx.x < off) red[threadIdx.x] += red[threadIdx.x + off];
            __syncthreads();
        }
        if (threadIdx.x == 0) {
            float E = red[0] / (float)((size_t)IN_CH * NUNITS);
            *scale = E / 7.0f;
        }
        __syncthreads();
    }
    __shared__ uint4 lds[64][5];
    const int t  = threadIdx.x;
    const int br = blockIdx.x >> 6;
    const int bc = blockIdx.x & 63;
    const int r  = t >> 2;
    const int cs = t & 3;
    const float4* xp = (const float4*)x + ((size_t)(br * 64 + r) * 1024 + bc * 16 + cs * 4);
    uint4 q;
    q.x = q4(xp[0]); q.y = q4(xp[1]); q.z = q4(xp[2]); q.w = q4(xp[3]);
    lds[r][cs] = q;
    __syncthreads();
    const int m    = t >> 6;
    const int lane = t & 63;
    uint4 o = lds[m * 16 + (lane & 15)][lane >> 4];
    *(uint4*)(af + ((((size_t)(br * 4 + m)) * 64 + bc) << 10) + lane * 16) = o;
}

// ---------------------------------------------------------------- GEMM
// 256x256 block tile, BK=64, 16 waves (4x4, wave tile 64x64), mfma_i32_16x16x64_i8.
// A: prefetched global fragment loads (ping-pong regs, 1 tile ahead).
// B: LDS, 3 buffers x 16KB; line L = B-row L (slots 0-3) || B-row L+128 (4-7);
// phys slot = logical ^ (L&7).
__device__ __forceinline__ void gload_lds16(const void* g, void* l) {
    __builtin_amdgcn_global_load_lds((const __attribute__((address_space(1))) void*)g,
                                     (__attribute__((address_space(3))) void*)l,
                                     16, 0, 0);
}

#define VMCNT1   asm volatile("s_waitcnt vmcnt(1)" ::: "memory")
#define VMCNT0   asm volatile("s_waitcnt vmcnt(0)" ::: "memory")
#define LGKM0    asm volatile("s_waitcnt lgkmcnt(0)" ::: "memory")
#define SCHEDB   __builtin_amdgcn_sched_barrier(0)
#define BARRIER  __builtin_amdgcn_s_barrier()
#define PRIO1    __builtin_amdgcn_s_setprio(1)
#define PRIO0    __builtin_amdgcn_s_setprio(0)

static constexpr int NT = IN_CH / 64;   // 64 K-tiles

__global__ __launch_bounds__(1024, 4) void k_gemm(const char* __restrict__ AF,
                                                  const char* __restrict__ BT,
                                                  const float* __restrict__ scale_p,
                                                  const float* __restrict__ bias,
                                                  float* __restrict__ out) {
    __shared__ char Bs[3][16384];   // 48 KiB

    const int t    = threadIdx.x;
    const int bid  = blockIdx.x;                  // 512 blocks
    const int swzb = (bid & 7) * 64 + (bid >> 3); // XCD swizzle (bijective)
    const int bRow = swzb >> 4;                   // 0..31
    const int bCol = swzb & 15;                   // 0..15
    const int lane = t & 63;
    const int wid  = t >> 6;                      // 0..15
    const int wr   = wid >> 2;                    // 0..3
    const int wc   = wid & 3;                     // 0..3
    const int lr   = lane & 15;
    const int lk4  = lane >> 4;                   // 0..3

    // A fragment base: mt = bRow*16 + wr*4 + m
    const char* aBaseF = AF + (((size_t)(bRow * 16 + wr * 4) * 64) << 10) + lane * 16;

    // B read offsets (per n): row R = wc*64 + n*16 + lr; line = R&127;
    // logical slot = (R>>7)*4 + lk4; phys = logical ^ (line&7)
    int boff[4];
#pragma unroll
    for (int n = 0; n < 4; ++n) {
        const int R    = wc * 64 + n * 16 + lr;
        const int line = R & 127;
        const int phys = (((R >> 7) << 2) | lk4) ^ (line & 7);
        boff[n] = line * 128 + phys * 16;
    }

    // B staging: thread t -> dest line t>>3, phys slot t&7 (linear dest t*16)
    const int x_    = (t & 7) ^ ((t >> 3) & 7);
    const int srow  = (t >> 3) + ((x_ >> 2) << 7);
    const char* sB  = BT + (size_t)(bCol * 256 + srow) * IN_CH + ((x_ & 3) << 4);

    v4i acc[4][4] = {};
    v4i aA[4], aB[4];

#define STAGE1(kt, STG)  gload_lds16(sB + (size_t)(kt) * 64, (STG) + t * 16)

#define LOADA(AN, kt)                                                            \
    _Pragma("unroll") for (int m = 0; m < 4; ++m)                                \
        AN[m] = *(const v4i*)(aBaseF + (((size_t)m * 64 + (kt)) << 10))

// Body: gate, barrier; issue LOADA(T+1) then STAGE(T+2); read b; MFMA with AC.
#define TILE(kt, CUR, STG, AC, AN, DOA, DOSTG, GATE)                             \
    do {                                                                         \
        SCHEDB; LGKM0;                                                           \
        GATE;                                                                    \
        BARRIER; SCHEDB;                                                         \
        if (DOA)   { LOADA(AN, (kt) + 1); }                                      \
        if (DOSTG) { STAGE1((kt) + 2, STG); }                                    \
        v4i b_[4];                                                               \
        _Pragma("unroll") for (int n = 0; n < 4; ++n)                            \
            b_[n] = *(const v4i*)((CUR) + boff[n]);                              \
        PRIO1;                                                                   \
        _Pragma("unroll") for (int m = 0; m < 4; ++m)                            \
            _Pragma("unroll") for (int n = 0; n < 4; ++n)                        \
                acc[m][n] = __builtin_amdgcn_mfma_i32_16x16x64_i8(               \
                    AC[m], b_[n], acc[m][n], 0, 0, 0);                           \
        PRIO0;                                                                   \
    } while (0)

    char* B0 = (char*)Bs[0];
    char* B1 = (char*)Bs[1];
    char* B2 = (char*)Bs[2];

    // prologue: stage B(0),B(1); load A(0) into aA.
    STAGE1(0, B0);
    STAGE1(1, B1);
    LOADA(aA, 0);

    // main: tiles 0..59, 6-tile unroll (lcm of 2-reg ping-pong and 3-buffer rot)
    for (int T = 0; T < 60; T += 6) {
        TILE(T + 0, B0, B2, aA, aB, 1, 1, VMCNT1);
        TILE(T + 1, B1, B0, aB, aA, 1, 1, VMCNT1);
        TILE(T + 2, B2, B1, aA, aB, 1, 1, VMCNT1);
        TILE(T + 3, B0, B2, aB, aA, 1, 1, VMCNT1);
        TILE(T + 4, B1, B0, aA, aB, 1, 1, VMCNT1);
        TILE(T + 5, B2, B1, aB, aA, 1, 1, VMCNT1);
    }
    // tail: 60..63
    TILE(60, B0, B2, aA, aB, 1, 1, VMCNT1);   // load A61, stage B62
    TILE(61, B1, B0, aB, aA, 1, 1, VMCNT1);   // load A62, stage B63
    TILE(62, B2, B1, aA, aB, 1, 0, VMCNT1);   // load A63
    TILE(63, B0, B1, aB, aA, 0, 0, VMCNT0);   // drain: A63 + B63 forced

    // ---- epilogue
    const float scale = *scale_p;
    const int orow0 = bRow * 256 + wr * 64;
    const int ocol0 = bCol * 256 + wc * 64;
#pragma unroll
    for (int m = 0; m < 4; ++m) {
#pragma unroll
        for (int n = 0; n < 4; ++n) {
            const int col = ocol0 + n * 16 + lr;
            const float bb = bias[col];
            const int rbase = orow0 + m * 16 + lk4 * 4;
#pragma unroll
            for (int j = 0; j < 4; ++j)
                out[(size_t)(rbase + j) * NUNITS + col] = scale * (float)acc[m][n][j] + bb;
        }
    }
#undef STAGE1
#undef LOADA
#undef TILE
}

// ---------------------------------------------------------------- launch
extern "C" void kernel_launch(void* const* d_in, const int* in_sizes, int n_in,
                              void* d_out, int out_size, void* d_ws, size_t ws_size,
                              hipStream_t stream) {
    const float* x  = (const float*)d_in[0];
    const float* W  = (const float*)d_in[1];
    const float* b  = (const float*)d_in[2];
    float* out      = (float*)d_out;

    char*  ws       = (char*)d_ws;
    char*  AF       = ws + AF_OFF;
    char*  BT       = ws + BT_OFF;
    float* partials = (float*)(ws + PART_OFF);
    float* scale    = (float*)(ws + SCALE_OFF);

    k_signT<<<(IN_CH / 64) * (NUNITS / 64), TPB, 0, stream>>>(W, BT, partials);
    k_quant_a<<<(BATCH / 64) * (IN_CH / 64), TPB, 0, stream>>>(x, AF, partials, scale);
    k_gemm<<<(BATCH / 256) * (NUNITS / 256), 1024, 0, stream>>>(AF, BT, scale, b, out);
}

// Round 14
// 166.927 us; speedup vs baseline: 1.3829x; 1.3829x over previous
//
#include <hip/hip_runtime.h>

// DoReFa dense: out = q_in(3-bit) @ (sign(W)*E) + b,  E = mean|W|
//   out[i,j] = (E/7) * sum_k r[i,k]*sign(W[k,j]),  r in 0..7 -- exact in i8 MFMA.
// R14: R11 champion (256^2, 16 waves 64x64, A64||B64 lines + XOR swizzle) with
//      BK=128 sync intervals: 2 x 64KB buffers, ONE barrier + ONE vmcnt gate per
//      128-K (32 vs 64 syncs). Stage 1 interval ahead (full-interval latency lead).

static constexpr int BATCH  = 8192;
static constexpr int IN_CH  = 4096;
static constexpr int NUNITS = 4096;
static constexpr int TPB    = 256;

typedef int v4i __attribute__((ext_vector_type(4)));

// ---- workspace layout ----
static constexpr size_t A8_OFF   = 0;
static constexpr size_t A8_BYTES = (size_t)BATCH * IN_CH;    // 32 MB
static constexpr size_t BT_OFF   = A8_OFF + A8_BYTES;
static constexpr size_t BT_BYTES = (size_t)NUNITS * IN_CH;   // 16 MB
static constexpr int    NPART    = 4096;
static constexpr size_t PART_OFF = BT_OFF + BT_BYTES;
static constexpr size_t SCALE_OFF= PART_OFF + NPART * sizeof(float);

// -------------------------- sign(W) transpose to [N][K]  +  fused |W| partial sum
__global__ __launch_bounds__(TPB) void k_signT(const float* __restrict__ W,
                                               char* __restrict__ bt,
                                               float* __restrict__ partials) {
    __shared__ char tile[64][68];
    __shared__ float red[TPB];
    const int bk = blockIdx.x & 63;
    const int bn = blockIdx.x >> 6;
    const int t  = threadIdx.x;
    const int c  = t & 63;
    const int r0 = t >> 6;
    float asum = 0.f;
#pragma unroll
    for (int i = 0; i < 16; ++i) {
        int r = i * 4 + r0;
        float w = W[(size_t)(bk * 64 + r) * NUNITS + bn * 64 + c];
        asum += fabsf(w);
        tile[c][r] = (w > 0.f) ? 1 : ((w < 0.f) ? -1 : 0);
    }
    __syncthreads();
    const int n  = t >> 2;
    const int kk = (t & 3) * 16;
    char o[16];
#pragma unroll
    for (int j = 0; j < 16; ++j) o[j] = tile[n][kk + j];
    *(uint4*)(bt + (size_t)(bn * 64 + n) * IN_CH + bk * 64 + kk) = *(const uint4*)o;

    red[t] = asum;
    __syncthreads();
    for (int off = TPB / 2; off > 0; off >>= 1) {
        if (t < off) red[t] += red[t + off];
        __syncthreads();
    }
    if (t == 0) partials[blockIdx.x] = red[0];
}

// ------------------------------------------------------------- quantize A (+ fused scale)
__device__ __forceinline__ unsigned int q4(float4 v) {
    unsigned int b0 = (unsigned int)(int)rintf(fminf(1.0f, fabsf(v.x)) * 7.0f);
    unsigned int b1 = (unsigned int)(int)rintf(fminf(1.0f, fabsf(v.y)) * 7.0f);
    unsigned int b2 = (unsigned int)(int)rintf(fminf(1.0f, fabsf(v.z)) * 7.0f);
    unsigned int b3 = (unsigned int)(int)rintf(fminf(1.0f, fabsf(v.w)) * 7.0f);
    return b0 | (b1 << 8) | (b2 << 16) | (b3 << 24);
}

__global__ __launch_bounds__(TPB) void k_quant_a(const float4* __restrict__ x4,
                                                 uint4* __restrict__ a16,
                                                 const float* __restrict__ partials,
                                                 float* __restrict__ scale) {
    if (blockIdx.x == 0) {
        __shared__ float red[TPB];
        float s = 0.f;
        for (int i = threadIdx.x; i < NPART; i += TPB) s += partials[i];
        red[threadIdx.x] = s;
        __syncthreads();
        for (int off = TPB / 2; off > 0; off >>= 1) {
            if ((int)threadIdx.x < off) red[threadIdx.x] += red[threadIdx.x + off];
            __syncthreads();
        }
        if (threadIdx.x == 0) {
            float E = red[0] / (float)((size_t)IN_CH * NUNITS);
            *scale = E / 7.0f;
        }
    }
    const size_t t = (size_t)blockIdx.x * TPB + threadIdx.x;
    uint4 o;
    o.x = q4(x4[t * 4 + 0]);
    o.y = q4(x4[t * 4 + 1]);
    o.z = q4(x4[t * 4 + 2]);
    o.w = q4(x4[t * 4 + 3]);
    a16[t] = o;
}

// ---------------------------------------------------------------- GEMM
// 256x256 block tile, interval BK=128 (2 k-chunks of 64), 16 waves (4x4, 64x64),
// mfma_i32_16x16x64_i8. LDS: 2 buffers x 64KB; each 32KB chunk = [256 lines][128B],
// line L = A-row L (64B) || B-row L (64B); 16B slot: phys = logical ^ (L&7).
__device__ __forceinline__ void gload_lds16(const void* g, void* l) {
    __builtin_amdgcn_global_load_lds((const __attribute__((address_space(1))) void*)g,
                                     (__attribute__((address_space(3))) void*)l,
                                     16, 0, 0);
}

#define VMCNT0   asm volatile("s_waitcnt vmcnt(0)" ::: "memory")
#define LGKM0    asm volatile("s_waitcnt lgkmcnt(0)" ::: "memory")
#define SCHEDB   __builtin_amdgcn_sched_barrier(0)
#define BARRIER  __builtin_amdgcn_s_barrier()
#define PRIO1    __builtin_amdgcn_s_setprio(1)
#define PRIO0    __builtin_amdgcn_s_setprio(0)

static constexpr int NI = IN_CH / 128;   // 32 intervals

__global__ __launch_bounds__(1024, 4) void k_gemm(const char* __restrict__ A8,
                                                  const char* __restrict__ BT,
                                                  const float* __restrict__ scale_p,
                                                  const float* __restrict__ bias,
                                                  float* __restrict__ out) {
    __shared__ char Ms[2][65536];   // 128 KiB

    const int t    = threadIdx.x;                 // 0..1023
    const int bid  = blockIdx.x;                  // 512 blocks
    const int swzb = (bid & 7) * 64 + (bid >> 3); // XCD swizzle (bijective: 512%8==0)
    const int bRow = swzb >> 4;                   // 0..31
    const int bCol = swzb & 15;                   // 0..15
    const int lane = t & 63;
    const int wid  = t >> 6;                      // 0..15
    const int wr   = wid >> 2;                    // 0..3
    const int wc   = wid & 3;                     // 0..3
    const int lr   = lane & 15;
    const int lk4  = lane >> 4;                   // 0..3

    const int aoff = ((lk4 ^ (lr & 7)) << 4);     // A logical slots 0..3
    const int boff = aoff ^ 64;                   // B logical slots 4..7

    const int lslot = (t & 7) ^ ((t >> 3) & 7);
    const char* mbase = (lslot < 4)
        ? (A8 + (size_t)(bRow * 256) * IN_CH)
        : (BT + (size_t)(bCol * 256) * IN_CH);
    const char* sbase = mbase + (size_t)(t >> 3) * IN_CH + ((lslot & 3) << 4);

    v4i acc[4][4] = {};

#define STAGE4(P, STG)                                                           \
    _Pragma("unroll") for (int c = 0; c < 2; ++c)                                \
        _Pragma("unroll") for (int h = 0; h < 2; ++h)                            \
            gload_lds16(sbase + (size_t)h * 128 * IN_CH + ((size_t)(P) * 128 + c * 64), \
                        (STG) + c * 32768 + h * 16384 + t * 16)

#define CHUNK(CUR, c)                                                            \
    do {                                                                         \
        const char* _cp = (CUR) + (c) * 32768;                                   \
        v4i a_[4], b_[4];                                                        \
        _Pragma("unroll") for (int m = 0; m < 4; ++m)                            \
            a_[m] = *(const v4i*)(_cp + (wr * 64 + m * 16 + lr) * 128 + aoff);   \
        _Pragma("unroll") for (int n = 0; n < 4; ++n)                            \
            b_[n] = *(const v4i*)(_cp + (wc * 64 + n * 16 + lr) * 128 + boff);   \
        PRIO1;                                                                   \
        _Pragma("unroll") for (int m = 0; m < 4; ++m)                            \
            _Pragma("unroll") for (int n = 0; n < 4; ++n)                        \
                acc[m][n] = __builtin_amdgcn_mfma_i32_16x16x64_i8(               \
                    a_[m], b_[n], acc[m][n], 0, 0, 0);                           \
        PRIO0;                                                                   \
    } while (0)

#define INTERVAL(P, CUR, STG, DOSTG)                                             \
    do {                                                                         \
        SCHEDB; LGKM0;                                                           \
        VMCNT0;                                                                  \
        BARRIER; SCHEDB;                                                         \
        if (DOSTG) { STAGE4((P) + 1, STG); }                                     \
        CHUNK(CUR, 0);                                                           \
        CHUNK(CUR, 1);                                                           \
    } while (0)

    char* B0 = (char*)Ms[0];
    char* B1 = (char*)Ms[1];

    // prologue: stage interval 0
    STAGE4(0, B0);

    // intervals 0..29 stage ahead; 30 stages 31; 31 stages nothing
    for (int P = 0; P < NI - 2; P += 2) {
        INTERVAL(P,     B0, B1, 1);
        INTERVAL(P + 1, B1, B0, 1);
    }
    INTERVAL(NI - 2, B0, B1, 1);   // P=30: stages 31
    INTERVAL(NI - 1, B1, B0, 0);   // P=31: compute only

    // ---- epilogue
    const float scale = *scale_p;
    const int orow0 = bRow * 256 + wr * 64;
    const int ocol0 = bCol * 256 + wc * 64;
#pragma unroll
    for (int m = 0; m < 4; ++m) {
#pragma unroll
        for (int n = 0; n < 4; ++n) {
            const int col = ocol0 + n * 16 + lr;
            const float bb = bias[col];
            const int rbase = orow0 + m * 16 + lk4 * 4;
#pragma unroll
            for (int j = 0; j < 4; ++j)
                out[(size_t)(rbase + j) * NUNITS + col] = scale * (float)acc[m][n][j] + bb;
        }
    }
#undef STAGE4
#undef CHUNK
#undef INTERVAL
}

// ---------------------------------------------------------------- launch
extern "C" void kernel_launch(void* const* d_in, const int* in_sizes, int n_in,
                              void* d_out, int out_size, void* d_ws, size_t ws_size,
                              hipStream_t stream) {
    const float* x  = (const float*)d_in[0];
    const float* W  = (const float*)d_in[1];
    const float* b  = (const float*)d_in[2];
    float* out      = (float*)d_out;

    char*  ws       = (char*)d_ws;
    char*  A8       = ws + A8_OFF;
    char*  BT       = ws + BT_OFF;
    float* partials = (float*)(ws + PART_OFF);
    float* scale    = (float*)(ws + SCALE_OFF);

    k_signT<<<(IN_CH / 64) * (NUNITS / 64), TPB, 0, stream>>>(W, BT, partials);
    k_quant_a<<<(BATCH * (IN_CH / 16)) / TPB, TPB, 0, stream>>>((const float4*)x, (uint4*)A8,
                                                                partials, scale);
    k_gemm<<<(BATCH / 256) * (NUNITS / 256), 1024, 0, stream>>>(A8, BT, scale, b, out);
}

// Round 15
// 166.703 us; speedup vs baseline: 1.3848x; 1.0013x over previous
//
#include <hip/hip_runtime.h>

// DoReFa dense: out = q_in(3-bit) @ (sign(W)*E) + b,  E = mean|W|
//   out[i,j] = (E/7) * sum_k r[i,k]*sign(W[k,j]),  r in 0..7 -- exact in i8 MFMA.
// R15: GEMM = R14 champion (unchanged: 256^2, 16 waves 4x4, BK=128 intervals,
//      2x64KB buffers, A64||B64 lines + XOR swizzle, 1 barrier/interval).
//      Preproc: k_signT W-reads vectorized float4 (was 16 scalar loads/thread).

static constexpr int BATCH  = 8192;
static constexpr int IN_CH  = 4096;
static constexpr int NUNITS = 4096;
static constexpr int TPB    = 256;

typedef int v4i __attribute__((ext_vector_type(4)));

// ---- workspace layout ----
static constexpr size_t A8_OFF   = 0;
static constexpr size_t A8_BYTES = (size_t)BATCH * IN_CH;    // 32 MB
static constexpr size_t BT_OFF   = A8_OFF + A8_BYTES;
static constexpr size_t BT_BYTES = (size_t)NUNITS * IN_CH;   // 16 MB
static constexpr int    NPART    = 4096;
static constexpr size_t PART_OFF = BT_OFF + BT_BYTES;
static constexpr size_t SCALE_OFF= PART_OFF + NPART * sizeof(float);

// -------------------------- sign(W) transpose to [N][K]  +  fused |W| partial sum
// W tile 64(k) x 64(n); float4-vectorized reads (4 rows x 16 threads x 16B / wave).
__global__ __launch_bounds__(TPB) void k_signT(const float* __restrict__ W,
                                               char* __restrict__ bt,
                                               float* __restrict__ partials) {
    __shared__ char tile[64][68];   // [n][k], +4 pad
    __shared__ float red[TPB];
    const int bk = blockIdx.x & 63;
    const int bn = blockIdx.x >> 6;
    const int t  = threadIdx.x;
    const int c4 = (t & 15) * 4;         // n-col base (4 cols)
    const int r0 = t >> 4;               // k-row base (stride 16)
    float asum = 0.f;
#pragma unroll
    for (int i = 0; i < 4; ++i) {
        const int r = i * 16 + r0;       // k_local
        float4 w = *(const float4*)(W + (size_t)(bk * 64 + r) * NUNITS + bn * 64 + c4);
        asum += fabsf(w.x) + fabsf(w.y) + fabsf(w.z) + fabsf(w.w);
        tile[c4 + 0][r] = (w.x > 0.f) ? 1 : ((w.x < 0.f) ? -1 : 0);
        tile[c4 + 1][r] = (w.y > 0.f) ? 1 : ((w.y < 0.f) ? -1 : 0);
        tile[c4 + 2][r] = (w.z > 0.f) ? 1 : ((w.z < 0.f) ? -1 : 0);
        tile[c4 + 3][r] = (w.w > 0.f) ? 1 : ((w.w < 0.f) ? -1 : 0);
    }
    __syncthreads();
    const int n  = t >> 2;
    const int kk = (t & 3) * 16;
    char o[16];
#pragma unroll
    for (int j = 0; j < 16; ++j) o[j] = tile[n][kk + j];
    *(uint4*)(bt + (size_t)(bn * 64 + n) * IN_CH + bk * 64 + kk) = *(const uint4*)o;

    red[t] = asum;
    __syncthreads();
    for (int off = TPB / 2; off > 0; off >>= 1) {
        if (t < off) red[t] += red[t + off];
        __syncthreads();
    }
    if (t == 0) partials[blockIdx.x] = red[0];
}

// ------------------------------------------------------------- quantize A (+ fused scale)
__device__ __forceinline__ unsigned int q4(float4 v) {
    unsigned int b0 = (unsigned int)(int)rintf(fminf(1.0f, fabsf(v.x)) * 7.0f);
    unsigned int b1 = (unsigned int)(int)rintf(fminf(1.0f, fabsf(v.y)) * 7.0f);
    unsigned int b2 = (unsigned int)(int)rintf(fminf(1.0f, fabsf(v.z)) * 7.0f);
    unsigned int b3 = (unsigned int)(int)rintf(fminf(1.0f, fabsf(v.w)) * 7.0f);
    return b0 | (b1 << 8) | (b2 << 16) | (b3 << 24);
}

__global__ __launch_bounds__(TPB) void k_quant_a(const float4* __restrict__ x4,
                                                 uint4* __restrict__ a16,
                                                 const float* __restrict__ partials,
                                                 float* __restrict__ scale) {
    if (blockIdx.x == 0) {
        __shared__ float red[TPB];
        float s = 0.f;
        for (int i = threadIdx.x; i < NPART; i += TPB) s += partials[i];
        red[threadIdx.x] = s;
        __syncthreads();
        for (int off = TPB / 2; off > 0; off >>= 1) {
            if ((int)threadIdx.x < off) red[threadIdx.x] += red[threadIdx.x + off];
            __syncthreads();
        }
        if (threadIdx.x == 0) {
            float E = red[0] / (float)((size_t)IN_CH * NUNITS);
            *scale = E / 7.0f;
        }
    }
    const size_t t = (size_t)blockIdx.x * TPB + threadIdx.x;
    uint4 o;
    o.x = q4(x4[t * 4 + 0]);
    o.y = q4(x4[t * 4 + 1]);
    o.z = q4(x4[t * 4 + 2]);
    o.w = q4(x4[t * 4 + 3]);
    a16[t] = o;
}

// ---------------------------------------------------------------- GEMM (R14 champion)
__device__ __forceinline__ void gload_lds16(const void* g, void* l) {
    __builtin_amdgcn_global_load_lds((const __attribute__((address_space(1))) void*)g,
                                     (__attribute__((address_space(3))) void*)l,
                                     16, 0, 0);
}

#define VMCNT0   asm volatile("s_waitcnt vmcnt(0)" ::: "memory")
#define LGKM0    asm volatile("s_waitcnt lgkmcnt(0)" ::: "memory")
#define SCHEDB   __builtin_amdgcn_sched_barrier(0)
#define BARRIER  __builtin_amdgcn_s_barrier()
#define PRIO1    __builtin_amdgcn_s_setprio(1)
#define PRIO0    __builtin_amdgcn_s_setprio(0)

static constexpr int NI = IN_CH / 128;   // 32 intervals

__global__ __launch_bounds__(1024, 4) void k_gemm(const char* __restrict__ A8,
                                                  const char* __restrict__ BT,
                                                  const float* __restrict__ scale_p,
                                                  const float* __restrict__ bias,
                                                  float* __restrict__ out) {
    __shared__ char Ms[2][65536];   // 128 KiB

    const int t    = threadIdx.x;                 // 0..1023
    const int bid  = blockIdx.x;                  // 512 blocks
    const int swzb = (bid & 7) * 64 + (bid >> 3); // XCD swizzle (bijective: 512%8==0)
    const int bRow = swzb >> 4;                   // 0..31
    const int bCol = swzb & 15;                   // 0..15
    const int lane = t & 63;
    const int wid  = t >> 6;                      // 0..15
    const int wr   = wid >> 2;                    // 0..3
    const int wc   = wid & 3;                     // 0..3
    const int lr   = lane & 15;
    const int lk4  = lane >> 4;                   // 0..3

    const int aoff = ((lk4 ^ (lr & 7)) << 4);     // A logical slots 0..3
    const int boff = aoff ^ 64;                   // B logical slots 4..7

    const int lslot = (t & 7) ^ ((t >> 3) & 7);
    const char* mbase = (lslot < 4)
        ? (A8 + (size_t)(bRow * 256) * IN_CH)
        : (BT + (size_t)(bCol * 256) * IN_CH);
    const char* sbase = mbase + (size_t)(t >> 3) * IN_CH + ((lslot & 3) << 4);

    v4i acc[4][4] = {};

#define STAGE4(P, STG)                                                           \
    _Pragma("unroll") for (int c = 0; c < 2; ++c)                                \
        _Pragma("unroll") for (int h = 0; h < 2; ++h)                            \
            gload_lds16(sbase + (size_t)h * 128 * IN_CH + ((size_t)(P) * 128 + c * 64), \
                        (STG) + c * 32768 + h * 16384 + t * 16)

#define CHUNK(CUR, c)                                                            \
    do {                                                                         \
        const char* _cp = (CUR) + (c) * 32768;                                   \
        v4i a_[4], b_[4];                                                        \
        _Pragma("unroll") for (int m = 0; m < 4; ++m)                            \
            a_[m] = *(const v4i*)(_cp + (wr * 64 + m * 16 + lr) * 128 + aoff);   \
        _Pragma("unroll") for (int n = 0; n < 4; ++n)                            \
            b_[n] = *(const v4i*)(_cp + (wc * 64 + n * 16 + lr) * 128 + boff);   \
        PRIO1;                                                                   \
        _Pragma("unroll") for (int m = 0; m < 4; ++m)                            \
            _Pragma("unroll") for (int n = 0; n < 4; ++n)                        \
                acc[m][n] = __builtin_amdgcn_mfma_i32_16x16x64_i8(               \
                    a_[m], b_[n], acc[m][n], 0, 0, 0);                           \
        PRIO0;                                                                   \
    } while (0)

#define INTERVAL(P, CUR, STG, DOSTG)                                             \
    do {                                                                         \
        SCHEDB; LGKM0;                                                           \
        VMCNT0;                                                                  \
        BARRIER; SCHEDB;                                                         \
        if (DOSTG) { STAGE4((P) + 1, STG); }                                     \
        CHUNK(CUR, 0);                                                           \
        CHUNK(CUR, 1);                                                           \
    } while (0)

    char* B0 = (char*)Ms[0];
    char* B1 = (char*)Ms[1];

    STAGE4(0, B0);

    for (int P = 0; P < NI - 2; P += 2) {
        INTERVAL(P,     B0, B1, 1);
        INTERVAL(P + 1, B1, B0, 1);
    }
    INTERVAL(NI - 2, B0, B1, 1);   // P=30: stages 31
    INTERVAL(NI - 1, B1, B0, 0);   // P=31: compute only

    // ---- epilogue
    const float scale = *scale_p;
    const int orow0 = bRow * 256 + wr * 64;
    const int ocol0 = bCol * 256 + wc * 64;
#pragma unroll
    for (int m = 0; m < 4; ++m) {
#pragma unroll
        for (int n = 0; n < 4; ++n) {
            const int col = ocol0 + n * 16 + lr;
            const float bb = bias[col];
            const int rbase = orow0 + m * 16 + lk4 * 4;
#pragma unroll
            for (int j = 0; j < 4; ++j)
                out[(size_t)(rbase + j) * NUNITS + col] = scale * (float)acc[m][n][j] + bb;
        }
    }
#undef STAGE4
#undef CHUNK
#undef INTERVAL
}

// ---------------------------------------------------------------- launch
extern "C" void kernel_launch(void* const* d_in, const int* in_sizes, int n_in,
                              void* d_out, int out_size, void* d_ws, size_t ws_size,
                              hipStream_t stream) {
    const float* x  = (const float*)d_in[0];
    const float* W  = (const float*)d_in[1];
    const float* b  = (const float*)d_in[2];
    float* out      = (float*)d_out;

    char*  ws       = (char*)d_ws;
    char*  A8       = ws + A8_OFF;
    char*  BT       = ws + BT_OFF;
    float* partials = (float*)(ws + PART_OFF);
    float* scale    = (float*)(ws + SCALE_OFF);

    k_signT<<<(IN_CH / 64) * (NUNITS / 64), TPB, 0, stream>>>(W, BT, partials);
    k_quant_a<<<(BATCH * (IN_CH / 16)) / TPB, TPB, 0, stream>>>((const float4*)x, (uint4*)A8,
                                                                partials, scale);
    k_gemm<<<(BATCH / 256) * (NUNITS / 256), 1024, 0, stream>>>(A8, BT, scale, b, out);
}